// Round 5
// baseline (710.752 us; speedup 1.0000x reference)
//
#include <hip/hip_runtime.h>
#include <hip/hip_bf16.h>

#define B_ 32
#define N_ 8192
#define DI_ 128
#define D_ 512
#define NC_ 1000
#define TN_ 128          // items per block
#define NT_ 64           // tiles = N_/TN_
#define LROW_ 520        // h1s row stride in shorts (pad +8)
#define XROW_ 136        // x_lds row stride in shorts (pad +8)

typedef short s8v __attribute__((ext_vector_type(8)));
typedef float f4v __attribute__((ext_vector_type(4)));

__device__ __forceinline__ unsigned short f2bf(float f){
  union { float f; unsigned u; } c; c.f = f;
  unsigned r = c.u + 0x7fffu + ((c.u >> 16) & 1u);
  return (unsigned short)(r >> 16);
}

// exact GELU: 0.5x(1+erf(x/sqrt2)); Abramowitz-Stegun 7.1.26, |err| <= 1.5e-7
__device__ __forceinline__ float gelu_f(float x){
  float ax = fabsf(x) * 0.70710678118654752f;
  float t = __builtin_amdgcn_rcpf(1.0f + 0.3275911f * ax);
  float poly = ((((1.061405429f*t - 1.453152027f)*t + 1.421413741f)*t
                 - 0.284496736f)*t + 0.254829592f)*t;
  float e = __expf(-ax*ax);
  float erf_ax = 1.0f - poly*e;
  erf_ax = (x >= 0.0f) ? erf_ax : -erf_ax;
  return 0.5f * x * (1.0f + erf_ax);
}

__device__ __forceinline__ float wsum64(float v){
  #pragma unroll
  for (int off = 32; off; off >>= 1) v += __shfl_xor(v, off, 64);
  return v;
}

// ---------------- prep: convert psi_x weights to bf16 ----------------
__global__ void k_prep(const float* __restrict__ w1, const float* __restrict__ w2,
                       unsigned short* __restrict__ w1b, unsigned short* __restrict__ w2b){
  int i = blockIdx.x * 256 + threadIdx.x;
  if (i < D_*DI_) w1b[i] = f2bf(w1[i]);
  if (i < D_*D_)  w2b[i] = f2bf(w2[i]);
}

// ---------------- query path: qk[b][d] = c * (k_w^T q)[d]; thread-per-output ----------------
__global__ __launch_bounds__(512)
void k_query(const float* __restrict__ xq,
             const float* __restrict__ w1q, const float* __restrict__ b1q,
             const float* __restrict__ w2q, const float* __restrict__ b2q,
             const float* __restrict__ qw,  const float* __restrict__ qb,
             const float* __restrict__ kw,
             float* __restrict__ qk_out){
  const int b = blockIdx.x;
  const int t = threadIdx.x;  // 512
  __shared__ float h1[D_], h2[D_], qv[D_];
  const float xv = xq[b];
  h1[t] = gelu_f(xv * w1q[t] + b1q[t]);
  __syncthreads();
  {
    const float4* r0 = (const float4*)(w2q + (size_t)t*D_);
    float a0 = 0.f;
    for (int kk = 0; kk < 128; ++kk){
      float4 hv = *(const float4*)&h1[kk*4];
      float4 w0 = r0[kk];
      a0 += w0.x*hv.x + w0.y*hv.y + w0.z*hv.z + w0.w*hv.w;
    }
    h2[t] = a0 + b2q[t];
  }
  __syncthreads();
  {
    const float4* r0 = (const float4*)(qw + (size_t)t*D_);
    float a0 = 0.f;
    for (int kk = 0; kk < 128; ++kk){
      float4 hv = *(const float4*)&h2[kk*4];
      float4 w0 = r0[kk];
      a0 += w0.x*hv.x + w0.y*hv.y + w0.z*hv.z + w0.w*hv.w;
    }
    qv[t] = a0 + qb[t];
  }
  __syncthreads();
  {
    float c0 = 0.f;
    for (int j = 0; j < D_; ++j) c0 += qv[j] * kw[(size_t)j*D_ + t];
    qk_out[b*D_ + t] = 0.04419417382415922f * c0;  // 512^-0.5
  }
}

// ---------------- main: 128 items/block, 512 thr (8 waves x 64 cols), r2 structure ----------------
__global__ __launch_bounds__(512, 2)
void k_main(const float* __restrict__ x,                 // [B,N,DI]
            const unsigned short* __restrict__ w1b,      // [D,DI] bf16
            const float* __restrict__ b1,
            const unsigned short* __restrict__ w2b,      // [D,D] bf16
            const float* __restrict__ b2,
            const float* __restrict__ qk,                // [B,D]
            float* __restrict__ part,                    // [B,NT,D]
            float* __restrict__ esum){                   // [B,NT]
  const int tile = blockIdx.x;       // 0..63
  const int b = blockIdx.y;          // 0..31
  const int n0 = tile * TN_;
  const int t = threadIdx.x;         // 0..511
  const int lane = t & 63;
  const int wid = t >> 6;            // 0..7
  const int ln = lane & 15;
  const int q  = lane >> 4;          // 0..3

  __shared__ unsigned short h1s[TN_ * LROW_];   // 133120 B; low part aliased as x_lds
  __shared__ float s_ws[8][TN_];
  __shared__ float e_lds[TN_];

  // ---- stage x tile to LDS as bf16 (x_lds aliases h1s[0..TN_*XROW_)) ----
  {
    const float4* xb4 = (const float4*)(x + ((size_t)b * N_ + n0) * DI_);
    #pragma unroll
    for (int i = 0; i < 8; ++i){
      const int f = i*512 + t;            // float4 index; 32 float4 per row
      float4 v = xb4[f];
      const int m = f >> 5;
      const int k = (f & 31) << 2;
      uint2 pk;
      pk.x = (unsigned)f2bf(v.x) | ((unsigned)f2bf(v.y) << 16);
      pk.y = (unsigned)f2bf(v.z) | ((unsigned)f2bf(v.w) << 16);
      *(uint2*)&h1s[m*XROW_ + k] = pk;
    }
  }
  __syncthreads();

  const int jb = wid * 64;              // this wave's 64-col j block
  f4v acc[32];
  #pragma unroll
  for (int i = 0; i < 32; ++i) acc[i] = (f4v){0.f,0.f,0.f,0.f};

  // ---- GEMM1: h1^T[j,m] = sum_k w1[j,k] * x[m,k] ----
  #pragma unroll
  for (int kk = 0; kk < 4; ++kk){
    const int k = kk*32 + q*8;
    s8v aw[4];
    #pragma unroll
    for (int jt = 0; jt < 4; ++jt)
      aw[jt] = *(const s8v*)(w1b + (jb + jt*16 + ln)*DI_ + k);
    s8v bx[8];
    #pragma unroll
    for (int mi = 0; mi < 8; ++mi)
      bx[mi] = *(const s8v*)&h1s[(mi*16 + ln)*XROW_ + k];
    #pragma unroll
    for (int jt = 0; jt < 4; ++jt)
      #pragma unroll
      for (int mi = 0; mi < 8; ++mi)
        acc[jt*8+mi] = __builtin_amdgcn_mfma_f32_16x16x32_bf16(aw[jt], bx[mi], acc[jt*8+mi], 0,0,0);
  }
  __syncthreads();   // all waves done reading x_lds before h1s overwrite

  // prefetch: GEMM2 k-step 0 w2 fragments + epilogue constants (hide L2 latency under GELU)
  s8v bw0[4];
  #pragma unroll
  for (int ni = 0; ni < 4; ++ni)
    bw0[ni] = *(const s8v*)(w2b + (size_t)(jb + ni*16 + ln)*D_ + q*8);
  float b2v[4], qkv[4];
  #pragma unroll
  for (int ni = 0; ni < 4; ++ni){
    const int j2 = jb + ni*16 + ln;
    b2v[ni] = b2[j2];
    qkv[ni] = qk[b*D_ + j2];
  }

  // ---- bias + exact GELU + pack to row-major h1s[m][k] ----
  #pragma unroll
  for (int jt = 0; jt < 4; ++jt){
    const int j0 = jb + jt*16 + q*4;
    const float bv0 = b1[j0], bv1 = b1[j0+1], bv2 = b1[j0+2], bv3 = b1[j0+3];
    #pragma unroll
    for (int mi = 0; mi < 8; ++mi){
      const int m = mi*16 + ln;
      f4v v = acc[jt*8+mi];
      uint2 pk;
      pk.x = (unsigned)f2bf(gelu_f(v[0]+bv0)) | ((unsigned)f2bf(gelu_f(v[1]+bv1)) << 16);
      pk.y = (unsigned)f2bf(gelu_f(v[2]+bv2)) | ((unsigned)f2bf(gelu_f(v[3]+bv3)) << 16);
      *(uint2*)&h1s[m*LROW_ + j0] = pk;
    }
  }
  __syncthreads();

  #pragma unroll
  for (int i = 0; i < 32; ++i) acc[i] = (f4v){0.f,0.f,0.f,0.f};

  // ---- GEMM2: h2[m,j2] = sum_k h1[m,k] * w2[j2,k]; wave owns 64 j2 cols ----
  // peeled k-step 0 using prefetched bw0
  {
    const int k = q*8;
    s8v ah[8];
    #pragma unroll
    for (int mi = 0; mi < 8; ++mi)
      ah[mi] = *(const s8v*)&h1s[(mi*16 + ln)*LROW_ + k];
    #pragma unroll
    for (int mi = 0; mi < 8; ++mi)
      #pragma unroll
      for (int ni = 0; ni < 4; ++ni)
        acc[mi*4+ni] = __builtin_amdgcn_mfma_f32_16x16x32_bf16(ah[mi], bw0[ni], acc[mi*4+ni], 0,0,0);
  }
  #pragma unroll 2
  for (int kk = 1; kk < 16; ++kk){
    const int k = kk*32 + q*8;
    s8v ah[8];
    #pragma unroll
    for (int mi = 0; mi < 8; ++mi)
      ah[mi] = *(const s8v*)&h1s[(mi*16 + ln)*LROW_ + k];
    s8v bw[4];
    #pragma unroll
    for (int ni = 0; ni < 4; ++ni)
      bw[ni] = *(const s8v*)(w2b + (size_t)(jb + ni*16 + ln)*D_ + k);
    #pragma unroll
    for (int mi = 0; mi < 8; ++mi)
      #pragma unroll
      for (int ni = 0; ni < 4; ++ni)
        acc[mi*4+ni] = __builtin_amdgcn_mfma_f32_16x16x32_bf16(ah[mi], bw[ni], acc[mi*4+ni], 0,0,0);
  }

  // ---- bias ----
  #pragma unroll
  for (int mi = 0; mi < 8; ++mi)
    #pragma unroll
    for (int ni = 0; ni < 4; ++ni)
      #pragma unroll
      for (int r = 0; r < 4; ++r)
        acc[mi*4+ni][r] += b2v[ni];

  // partial scores over this wave's 64 cols (m = mi*16 + q*4 + r, col = ln)
  #pragma unroll
  for (int mi = 0; mi < 8; ++mi){
    #pragma unroll
    for (int r = 0; r < 4; ++r){
      float sp = 0.f;
      #pragma unroll
      for (int ni = 0; ni < 4; ++ni) sp += qkv[ni] * acc[mi*4+ni][r];
      sp += __shfl_xor(sp, 1, 64);
      sp += __shfl_xor(sp, 2, 64);
      sp += __shfl_xor(sp, 4, 64);
      sp += __shfl_xor(sp, 8, 64);
      if (ln == ((mi*4 + r) & 15)) s_ws[wid][mi*16 + q*4 + r] = sp;
    }
  }
  __syncthreads();

  if (t < TN_){
    float s = 0.f;
    #pragma unroll
    for (int w = 0; w < 8; ++w) s += s_ws[w][t];
    e_lds[t] = __expf(s);   // |s| small; constant shift cancels in softmax
  }
  __syncthreads();
  if (t < 64){
    float tot = wsum64(e_lds[t] + e_lds[t+64]);
    if (t == 0) esum[b*NT_ + tile] = tot;
  }

  // weighted h2 partial: part[b][tile][col] = sum_m e_m * h2[m,col]
  {
    float ev[8][4];
    #pragma unroll
    for (int mi = 0; mi < 8; ++mi)
      #pragma unroll
      for (int r = 0; r < 4; ++r)
        ev[mi][r] = e_lds[mi*16 + q*4 + r];
    #pragma unroll
    for (int ni = 0; ni < 4; ++ni){
      float zp = 0.f;
      #pragma unroll
      for (int mi = 0; mi < 8; ++mi)
        #pragma unroll
        for (int r = 0; r < 4; ++r)
          zp += ev[mi][r] * acc[mi*4+ni][r];
      zp += __shfl_xor(zp, 16, 64);
      zp += __shfl_xor(zp, 32, 64);
      if (lane < 16)
        part[((size_t)(b*NT_ + tile))*D_ + jb + ni*16 + ln] = zp;
    }
  }
}

// ---------------- final: reduce partials, v_w GEMV, phi MLP, logits; one kernel ----------------
__global__ __launch_bounds__(512)
void k_final(const float* __restrict__ part, const float* __restrict__ esum,
             const float* __restrict__ vw, const float* __restrict__ vb,
             const float* __restrict__ pw1, const float* __restrict__ pb1,
             const float* __restrict__ pw2, const float* __restrict__ pb2,
             float* __restrict__ out){
  const int b = blockIdx.x;
  const int t = threadIdx.x;  // 512
  __shared__ float u[D_], z[D_], h[D_];
  __shared__ float linv_s;
  if (t < 64){
    float p = wsum64(esum[b*NT_ + t]);
    if (t == 0) linv_s = 1.0f / p;
  }
  __syncthreads();
  const float linv = linv_s;
  {
    const float* pb = part + (size_t)b*NT_*D_;
    float s0 = 0.f;
    for (int tl = 0; tl < NT_; ++tl) s0 += pb[tl*D_ + t];
    u[t] = s0 * linv;
  }
  __syncthreads();
  {
    const float4* r0 = (const float4*)(vw + (size_t)t*D_);
    float a0 = 0.f;
    for (int kk = 0; kk < 128; ++kk){
      float4 uv = *(const float4*)&u[kk*4];
      float4 w0 = r0[kk];
      a0 += w0.x*uv.x + w0.y*uv.y + w0.z*uv.z + w0.w*uv.w;
    }
    z[t] = a0 + vb[t];
  }
  __syncthreads();
  {
    const float4* r0 = (const float4*)(pw1 + (size_t)t*D_);
    float a0 = 0.f;
    for (int kk = 0; kk < 128; ++kk){
      float4 zv = *(const float4*)&z[kk*4];
      float4 w0 = r0[kk];
      a0 += w0.x*zv.x + w0.y*zv.y + w0.z*zv.z + w0.w*zv.w;
    }
    h[t] = gelu_f(a0 + pb1[t]);
  }
  __syncthreads();
  #pragma unroll
  for (int cc = 0; cc < 2; ++cc){
    const int c = t + cc*512;
    if (c < NC_){
      const float4* rw = (const float4*)(pw2 + (size_t)c*D_);
      float a = 0.f;
      for (int kk = 0; kk < 128; ++kk){
        float4 hv = *(const float4*)&h[kk*4];
        float4 wv = rw[kk];
        a += wv.x*hv.x + wv.y*hv.y + wv.z*hv.z + wv.w*hv.w;
      }
      out[(size_t)b*NC_ + c] = a + pb2[c];
    }
  }
}

extern "C" void kernel_launch(void* const* d_in, const int* in_sizes, int n_in,
                              void* d_out, int out_size, void* d_ws, size_t ws_size,
                              hipStream_t stream) {
  (void)in_sizes; (void)n_in; (void)out_size; (void)ws_size;
  const float* x_items  = (const float*)d_in[0];
  const float* x_query  = (const float*)d_in[1];
  const float* psi_x_w1 = (const float*)d_in[2];
  const float* psi_x_b1 = (const float*)d_in[3];
  const float* psi_x_w2 = (const float*)d_in[4];
  const float* psi_x_b2 = (const float*)d_in[5];
  const float* psi_q_w1 = (const float*)d_in[6];
  const float* psi_q_b1 = (const float*)d_in[7];
  const float* psi_q_w2 = (const float*)d_in[8];
  const float* psi_q_b2 = (const float*)d_in[9];
  const float* q_w      = (const float*)d_in[10];
  const float* q_b      = (const float*)d_in[11];
  const float* k_w      = (const float*)d_in[12];
  // k_b (d_in[13]) unused: constant score shift cancels in softmax
  const float* v_w      = (const float*)d_in[14];
  const float* v_b      = (const float*)d_in[15];
  const float* phi_w1   = (const float*)d_in[16];
  const float* phi_b1   = (const float*)d_in[17];
  const float* phi_w2   = (const float*)d_in[18];
  const float* phi_b2   = (const float*)d_in[19];
  float* out = (float*)d_out;

  char* ws = (char*)d_ws;
  unsigned short* w1b = (unsigned short*)(ws);                 // 512*128*2  = 131072
  unsigned short* w2b = (unsigned short*)(ws + 131072);        // 512*512*2  = 524288
  float* qk   = (float*)(ws + 655360);                         // 32*512*4   = 65536
  float* part = (float*)(ws + 720896);                         // 32*64*512*4 = 4194304
  float* esum = (float*)(ws + 720896 + 4194304);               // 32*64*4    = 8192

  hipLaunchKernelGGL(k_prep, dim3(1024), dim3(256), 0, stream,
                     psi_x_w1, psi_x_w2, w1b, w2b);
  hipLaunchKernelGGL(k_query, dim3(32), dim3(512), 0, stream,
                     x_query, psi_q_w1, psi_q_b1, psi_q_w2, psi_q_b2,
                     q_w, q_b, k_w, qk);
  hipLaunchKernelGGL(k_main, dim3(NT_, B_), dim3(512), 0, stream,
                     x_items, w1b, psi_x_b1, w2b, psi_x_b2, qk, part, esum);
  hipLaunchKernelGGL(k_final, dim3(32), dim3(512), 0, stream,
                     part, esum, v_w, v_b, phi_w1, phi_b1, phi_w2, phi_b2, out);
}

// Round 6
// 648.611 us; speedup vs baseline: 1.0958x; 1.0958x over previous
//
#include <hip/hip_runtime.h>
#include <hip/hip_bf16.h>

#define B_ 32
#define N_ 8192
#define DI_ 128
#define D_ 512
#define NC_ 1000
#define TN_ 128          // items per block
#define NT_ 64           // tiles = N_/TN_
#define LROW_ 520        // h1s row stride in shorts (pad +8)
#define XROW_ 136        // x_lds row stride in shorts (pad +8)

typedef short s8v __attribute__((ext_vector_type(8)));
typedef float f4v __attribute__((ext_vector_type(4)));

__device__ __forceinline__ unsigned short f2bf(float f){
  union { float f; unsigned u; } c; c.f = f;
  unsigned r = c.u + 0x7fffu + ((c.u >> 16) & 1u);
  return (unsigned short)(r >> 16);
}

// exact GELU: 0.5x(1+erf(x/sqrt2)); Abramowitz-Stegun 7.1.26, |err| <= 1.5e-7
__device__ __forceinline__ float gelu_f(float x){
  float ax = fabsf(x) * 0.70710678118654752f;
  float t = __builtin_amdgcn_rcpf(1.0f + 0.3275911f * ax);
  float poly = ((((1.061405429f*t - 1.453152027f)*t + 1.421413741f)*t
                 - 0.284496736f)*t + 0.254829592f)*t;
  float e = __expf(-ax*ax);
  float erf_ax = 1.0f - poly*e;
  erf_ax = (x >= 0.0f) ? erf_ax : -erf_ax;
  return 0.5f * x * (1.0f + erf_ax);
}

__device__ __forceinline__ float wsum64(float v){
  #pragma unroll
  for (int off = 32; off; off >>= 1) v += __shfl_xor(v, off, 64);
  return v;
}

// ---------------- prep: convert psi_x weights to bf16 in MFMA fragment order ----------------
// element (j, kc) with kc = kk*32 + q*8 + s  ->  packed[((kk*512 + j)*4 + q)*8 + s]
// so a wave's fragment load (lanes (q,ln), rows jb+ni*16+ln) is 1 KB contiguous.
__global__ void k_prep(const float* __restrict__ w1, const float* __restrict__ w2,
                       unsigned short* __restrict__ w1p, unsigned short* __restrict__ w2p){
  int i = blockIdx.x * 256 + threadIdx.x;
  if (i < D_*DI_){
    int j = i / DI_, kc = i % DI_;
    int kk = kc >> 5, q = (kc >> 3) & 3, s = kc & 7;
    w1p[((kk*D_ + j)*4 + q)*8 + s] = f2bf(w1[i]);
  }
  if (i < D_*D_){
    int j = i / D_, kc = i % D_;
    int kk = kc >> 5, q = (kc >> 3) & 3, s = kc & 7;
    w2p[((kk*D_ + j)*4 + q)*8 + s] = f2bf(w2[i]);
  }
}

// ---------------- query path: qk[b][d] = c * (k_w^T q)[d]; thread-per-output ----------------
__global__ __launch_bounds__(512)
void k_query(const float* __restrict__ xq,
             const float* __restrict__ w1q, const float* __restrict__ b1q,
             const float* __restrict__ w2q, const float* __restrict__ b2q,
             const float* __restrict__ qw,  const float* __restrict__ qb,
             const float* __restrict__ kw,
             float* __restrict__ qk_out){
  const int b = blockIdx.x;
  const int t = threadIdx.x;  // 512
  __shared__ float h1[D_], h2[D_], qv[D_];
  const float xv = xq[b];
  h1[t] = gelu_f(xv * w1q[t] + b1q[t]);
  __syncthreads();
  {
    const float4* r0 = (const float4*)(w2q + (size_t)t*D_);
    float a0 = 0.f;
    for (int kk = 0; kk < 128; ++kk){
      float4 hv = *(const float4*)&h1[kk*4];
      float4 w0 = r0[kk];
      a0 += w0.x*hv.x + w0.y*hv.y + w0.z*hv.z + w0.w*hv.w;
    }
    h2[t] = a0 + b2q[t];
  }
  __syncthreads();
  {
    const float4* r0 = (const float4*)(qw + (size_t)t*D_);
    float a0 = 0.f;
    for (int kk = 0; kk < 128; ++kk){
      float4 hv = *(const float4*)&h2[kk*4];
      float4 w0 = r0[kk];
      a0 += w0.x*hv.x + w0.y*hv.y + w0.z*hv.z + w0.w*hv.w;
    }
    qv[t] = a0 + qb[t];
  }
  __syncthreads();
  {
    float c0 = 0.f;
    for (int j = 0; j < D_; ++j) c0 += qv[j] * kw[(size_t)j*D_ + t];
    qk_out[b*D_ + t] = 0.04419417382415922f * c0;  // 512^-0.5
  }
}

// ---------------- main: 128 items/block, 512 thr (8 waves x 64 cols), r2 structure + packed weights ----------------
__global__ __launch_bounds__(512, 2)
void k_main(const float* __restrict__ x,                 // [B,N,DI]
            const unsigned short* __restrict__ w1p,      // packed bf16
            const float* __restrict__ b1,
            const unsigned short* __restrict__ w2p,      // packed bf16
            const float* __restrict__ b2,
            const float* __restrict__ qk,                // [B,D]
            float* __restrict__ part,                    // [B,NT,D]
            float* __restrict__ esum){                   // [B,NT]
  const int tile = blockIdx.x;       // 0..63
  const int b = blockIdx.y;          // 0..31
  const int n0 = tile * TN_;
  const int t = threadIdx.x;         // 0..511
  const int lane = t & 63;
  const int wid = t >> 6;            // 0..7
  const int ln = lane & 15;
  const int q  = lane >> 4;          // 0..3

  __shared__ unsigned short h1s[TN_ * LROW_];   // 133120 B; low part aliased as x_lds
  __shared__ float s_ws[8][TN_];
  __shared__ float e_lds[TN_];

  // ---- stage x tile to LDS as bf16 (x_lds aliases h1s[0..TN_*XROW_)) ----
  {
    const float4* xb4 = (const float4*)(x + ((size_t)b * N_ + n0) * DI_);
    #pragma unroll
    for (int i = 0; i < 8; ++i){
      const int f = i*512 + t;            // float4 index; 32 float4 per row
      float4 v = xb4[f];
      const int m = f >> 5;
      const int k = (f & 31) << 2;
      uint2 pk;
      pk.x = (unsigned)f2bf(v.x) | ((unsigned)f2bf(v.y) << 16);
      pk.y = (unsigned)f2bf(v.z) | ((unsigned)f2bf(v.w) << 16);
      *(uint2*)&h1s[m*XROW_ + k] = pk;
    }
  }
  __syncthreads();

  const int jb = wid * 64;              // this wave's 64-col j block
  // packed-fragment base for this lane: rows (jb+ln), quad q
  const unsigned short* w1base = w1p + (jb + ln)*32 + q*8;
  const unsigned short* w2base = w2p + (jb + ln)*32 + q*8;

  f4v acc[32];
  #pragma unroll
  for (int i = 0; i < 32; ++i) acc[i] = (f4v){0.f,0.f,0.f,0.f};

  // ---- GEMM1: h1^T[j,m] = sum_k w1[j,k] * x[m,k] ----
  #pragma unroll
  for (int kk = 0; kk < 4; ++kk){
    const int k = kk*32 + q*8;
    s8v aw[4];
    #pragma unroll
    for (int jt = 0; jt < 4; ++jt)
      aw[jt] = *(const s8v*)(w1base + kk*(D_*32) + jt*(16*32));
    s8v bx[8];
    #pragma unroll
    for (int mi = 0; mi < 8; ++mi)
      bx[mi] = *(const s8v*)&h1s[(mi*16 + ln)*XROW_ + k];
    #pragma unroll
    for (int jt = 0; jt < 4; ++jt)
      #pragma unroll
      for (int mi = 0; mi < 8; ++mi)
        acc[jt*8+mi] = __builtin_amdgcn_mfma_f32_16x16x32_bf16(aw[jt], bx[mi], acc[jt*8+mi], 0,0,0);
  }
  __syncthreads();   // all waves done reading x_lds before h1s overwrite

  // ---- bias + exact GELU + pack to row-major h1s[m][k] ----
  #pragma unroll
  for (int jt = 0; jt < 4; ++jt){
    const int j0 = jb + jt*16 + q*4;
    const float bv0 = b1[j0], bv1 = b1[j0+1], bv2 = b1[j0+2], bv3 = b1[j0+3];
    #pragma unroll
    for (int mi = 0; mi < 8; ++mi){
      const int m = mi*16 + ln;
      f4v v = acc[jt*8+mi];
      uint2 pk;
      pk.x = (unsigned)f2bf(gelu_f(v[0]+bv0)) | ((unsigned)f2bf(gelu_f(v[1]+bv1)) << 16);
      pk.y = (unsigned)f2bf(gelu_f(v[2]+bv2)) | ((unsigned)f2bf(gelu_f(v[3]+bv3)) << 16);
      *(uint2*)&h1s[m*LROW_ + j0] = pk;
    }
  }
  __syncthreads();

  #pragma unroll
  for (int i = 0; i < 32; ++i) acc[i] = (f4v){0.f,0.f,0.f,0.f};

  // ---- GEMM2: h2[m,j2] = sum_k h1[m,k] * w2[j2,k]; wave owns 64 j2 cols ----
  #pragma unroll 2
  for (int kk = 0; kk < 16; ++kk){
    const int k = kk*32 + q*8;
    s8v ah[8];
    #pragma unroll
    for (int mi = 0; mi < 8; ++mi)
      ah[mi] = *(const s8v*)&h1s[(mi*16 + ln)*LROW_ + k];
    s8v bw[4];
    #pragma unroll
    for (int ni = 0; ni < 4; ++ni)
      bw[ni] = *(const s8v*)(w2base + kk*(D_*32) + ni*(16*32));
    #pragma unroll
    for (int mi = 0; mi < 8; ++mi)
      #pragma unroll
      for (int ni = 0; ni < 4; ++ni)
        acc[mi*4+ni] = __builtin_amdgcn_mfma_f32_16x16x32_bf16(ah[mi], bw[ni], acc[mi*4+ni], 0,0,0);
  }

  // ---- bias + qk dot (loaded after GEMM2: keeps loop register pressure minimal) ----
  float b2v[4], qkv[4];
  #pragma unroll
  for (int ni = 0; ni < 4; ++ni){
    const int j2 = jb + ni*16 + ln;
    b2v[ni] = b2[j2];
    qkv[ni] = qk[b*D_ + j2];
  }
  #pragma unroll
  for (int mi = 0; mi < 8; ++mi)
    #pragma unroll
    for (int ni = 0; ni < 4; ++ni)
      #pragma unroll
      for (int r = 0; r < 4; ++r)
        acc[mi*4+ni][r] += b2v[ni];

  // partial scores over this wave's 64 cols (m = mi*16 + q*4 + r, col = ln)
  #pragma unroll
  for (int mi = 0; mi < 8; ++mi){
    #pragma unroll
    for (int r = 0; r < 4; ++r){
      float sp = 0.f;
      #pragma unroll
      for (int ni = 0; ni < 4; ++ni) sp += qkv[ni] * acc[mi*4+ni][r];
      sp += __shfl_xor(sp, 1, 64);
      sp += __shfl_xor(sp, 2, 64);
      sp += __shfl_xor(sp, 4, 64);
      sp += __shfl_xor(sp, 8, 64);
      if (ln == ((mi*4 + r) & 15)) s_ws[wid][mi*16 + q*4 + r] = sp;
    }
  }
  __syncthreads();

  if (t < TN_){
    float s = 0.f;
    #pragma unroll
    for (int w = 0; w < 8; ++w) s += s_ws[w][t];
    e_lds[t] = __expf(s);   // |s| small; constant shift cancels in softmax
  }
  __syncthreads();
  if (t < 64){
    float tot = wsum64(e_lds[t] + e_lds[t+64]);
    if (t == 0) esum[b*NT_ + tile] = tot;
  }

  // weighted h2 partial: part[b][tile][col] = sum_m e_m * h2[m,col]
  {
    float ev[8][4];
    #pragma unroll
    for (int mi = 0; mi < 8; ++mi)
      #pragma unroll
      for (int r = 0; r < 4; ++r)
        ev[mi][r] = e_lds[mi*16 + q*4 + r];
    #pragma unroll
    for (int ni = 0; ni < 4; ++ni){
      float zp = 0.f;
      #pragma unroll
      for (int mi = 0; mi < 8; ++mi)
        #pragma unroll
        for (int r = 0; r < 4; ++r)
          zp += ev[mi][r] * acc[mi*4+ni][r];
      zp += __shfl_xor(zp, 16, 64);
      zp += __shfl_xor(zp, 32, 64);
      if (lane < 16)
        part[((size_t)(b*NT_ + tile))*D_ + jb + ni*16 + ln] = zp;
    }
  }
}

// ---------------- final: reduce partials, v_w GEMV, phi MLP, logits; one kernel ----------------
__global__ __launch_bounds__(512)
void k_final(const float* __restrict__ part, const float* __restrict__ esum,
             const float* __restrict__ vw, const float* __restrict__ vb,
             const float* __restrict__ pw1, const float* __restrict__ pb1,
             const float* __restrict__ pw2, const float* __restrict__ pb2,
             float* __restrict__ out){
  const int b = blockIdx.x;
  const int t = threadIdx.x;  // 512
  __shared__ float u[D_], z[D_], h[D_];
  __shared__ float linv_s;
  if (t < 64){
    float p = wsum64(esum[b*NT_ + t]);
    if (t == 0) linv_s = 1.0f / p;
  }
  __syncthreads();
  const float linv = linv_s;
  {
    const float* pb = part + (size_t)b*NT_*D_;
    float s0 = 0.f;
    for (int tl = 0; tl < NT_; ++tl) s0 += pb[tl*D_ + t];
    u[t] = s0 * linv;
  }
  __syncthreads();
  {
    const float4* r0 = (const float4*)(vw + (size_t)t*D_);
    float a0 = 0.f;
    for (int kk = 0; kk < 128; ++kk){
      float4 uv = *(const float4*)&u[kk*4];
      float4 w0 = r0[kk];
      a0 += w0.x*uv.x + w0.y*uv.y + w0.z*uv.z + w0.w*uv.w;
    }
    z[t] = a0 + vb[t];
  }
  __syncthreads();
  {
    const float4* r0 = (const float4*)(pw1 + (size_t)t*D_);
    float a0 = 0.f;
    for (int kk = 0; kk < 128; ++kk){
      float4 zv = *(const float4*)&z[kk*4];
      float4 w0 = r0[kk];
      a0 += w0.x*zv.x + w0.y*zv.y + w0.z*zv.z + w0.w*zv.w;
    }
    h[t] = gelu_f(a0 + pb1[t]);
  }
  __syncthreads();
  #pragma unroll
  for (int cc = 0; cc < 2; ++cc){
    const int c = t + cc*512;
    if (c < NC_){
      const float4* rw = (const float4*)(pw2 + (size_t)c*D_);
      float a = 0.f;
      for (int kk = 0; kk < 128; ++kk){
        float4 hv = *(const float4*)&h[kk*4];
        float4 wv = rw[kk];
        a += wv.x*hv.x + wv.y*hv.y + wv.z*hv.z + wv.w*hv.w;
      }
      out[(size_t)b*NC_ + c] = a + pb2[c];
    }
  }
}

extern "C" void kernel_launch(void* const* d_in, const int* in_sizes, int n_in,
                              void* d_out, int out_size, void* d_ws, size_t ws_size,
                              hipStream_t stream) {
  (void)in_sizes; (void)n_in; (void)out_size; (void)ws_size;
  const float* x_items  = (const float*)d_in[0];
  const float* x_query  = (const float*)d_in[1];
  const float* psi_x_w1 = (const float*)d_in[2];
  const float* psi_x_b1 = (const float*)d_in[3];
  const float* psi_x_w2 = (const float*)d_in[4];
  const float* psi_x_b2 = (const float*)d_in[5];
  const float* psi_q_w1 = (const float*)d_in[6];
  const float* psi_q_b1 = (const float*)d_in[7];
  const float* psi_q_w2 = (const float*)d_in[8];
  const float* psi_q_b2 = (const float*)d_in[9];
  const float* q_w      = (const float*)d_in[10];
  const float* q_b      = (const float*)d_in[11];
  const float* k_w      = (const float*)d_in[12];
  // k_b (d_in[13]) unused: constant score shift cancels in softmax
  const float* v_w      = (const float*)d_in[14];
  const float* v_b      = (const float*)d_in[15];
  const float* phi_w1   = (const float*)d_in[16];
  const float* phi_b1   = (const float*)d_in[17];
  const float* phi_w2   = (const float*)d_in[18];
  const float* phi_b2   = (const float*)d_in[19];
  float* out = (float*)d_out;

  char* ws = (char*)d_ws;
  unsigned short* w1p = (unsigned short*)(ws);                 // 512*128*2  = 131072
  unsigned short* w2p = (unsigned short*)(ws + 131072);        // 512*512*2  = 524288
  float* qk   = (float*)(ws + 655360);                         // 32*512*4   = 65536
  float* part = (float*)(ws + 720896);                         // 32*64*512*4 = 4194304
  float* esum = (float*)(ws + 720896 + 4194304);               // 32*64*4    = 8192

  hipLaunchKernelGGL(k_prep, dim3(1024), dim3(256), 0, stream,
                     psi_x_w1, psi_x_w2, w1p, w2p);
  hipLaunchKernelGGL(k_query, dim3(32), dim3(512), 0, stream,
                     x_query, psi_q_w1, psi_q_b1, psi_q_w2, psi_q_b2,
                     q_w, q_b, k_w, qk);
  hipLaunchKernelGGL(k_main, dim3(NT_, B_), dim3(512), 0, stream,
                     x_items, w1p, psi_x_b1, w2p, psi_x_b2, qk, part, esum);
  hipLaunchKernelGGL(k_final, dim3(32), dim3(512), 0, stream,
                     part, esum, v_w, v_b, phi_w1, phi_b1, phi_w2, phi_b2, out);
}

// Round 7
// 539.042 us; speedup vs baseline: 1.3185x; 1.2033x over previous
//
#include <hip/hip_runtime.h>
#include <hip/hip_bf16.h>

#define B_ 32
#define N_ 8192
#define DI_ 128
#define D_ 512
#define NC_ 1000
#define TN_ 128          // items per block
#define NT_ 64           // tiles = N_/TN_
#define LROW_ 520        // h1s row stride in shorts (pad +8)
#define XROW_ 136        // x_lds row stride in shorts (pad +8)

typedef short s8v __attribute__((ext_vector_type(8)));
typedef float f4v __attribute__((ext_vector_type(4)));

__device__ __forceinline__ unsigned short f2bf(float f){
  union { float f; unsigned u; } c; c.f = f;
  unsigned r = c.u + 0x7fffu + ((c.u >> 16) & 1u);
  return (unsigned short)(r >> 16);
}

// hardware v_cvt_pk_bf16_f32: 2 floats -> packed bf16 (RNE), a in low 16
__device__ __forceinline__ unsigned pk2bf(float a, float b){
  float2 f; f.x = a; f.y = b;
  __hip_bfloat162 h = __float22bfloat162_rn(f);
  union { __hip_bfloat162 h; unsigned u; } c; c.h = h;
  return c.u;
}

// exact GELU: 0.5x(1+erf(x/sqrt2)); Abramowitz-Stegun 7.1.26, |err| <= 1.5e-7
__device__ __forceinline__ float gelu_f(float x){
  float ax = fabsf(x) * 0.70710678118654752f;
  float t = __builtin_amdgcn_rcpf(1.0f + 0.3275911f * ax);
  float poly = ((((1.061405429f*t - 1.453152027f)*t + 1.421413741f)*t
                 - 0.284496736f)*t + 0.254829592f)*t;
  float e = __expf(-ax*ax);
  float erf_ax = 1.0f - poly*e;
  erf_ax = (x >= 0.0f) ? erf_ax : -erf_ax;
  return 0.5f * x * (1.0f + erf_ax);
}

__device__ __forceinline__ float wsum64(float v){
  #pragma unroll
  for (int off = 32; off; off >>= 1) v += __shfl_xor(v, off, 64);
  return v;
}

// ---------------- prep: convert psi_x weights to bf16 in MFMA fragment order ----------------
__global__ void k_prep(const float* __restrict__ w1, const float* __restrict__ w2,
                       unsigned short* __restrict__ w1p, unsigned short* __restrict__ w2p){
  int i = blockIdx.x * 256 + threadIdx.x;
  if (i < D_*DI_){
    int j = i / DI_, kc = i % DI_;
    int kk = kc >> 5, q = (kc >> 3) & 3, s = kc & 7;
    w1p[((kk*D_ + j)*4 + q)*8 + s] = f2bf(w1[i]);
  }
  if (i < D_*D_){
    int j = i / D_, kc = i % D_;
    int kk = kc >> 5, q = (kc >> 3) & 3, s = kc & 7;
    w2p[((kk*D_ + j)*4 + q)*8 + s] = f2bf(w2[i]);
  }
}

// ---------------- query path, wide: grid (32, 8) x 64 ----------------
// stage 1: h2 = w2q @ gelu(xv*w1q + b1q) + b2q   (h1 recomputed per block, trivial)
__global__ __launch_bounds__(64)
void k_q2(const float* __restrict__ xq,
          const float* __restrict__ w1q, const float* __restrict__ b1q,
          const float* __restrict__ w2q, const float* __restrict__ b2q,
          float* __restrict__ h2g){
  const int b = blockIdx.x, sl = blockIdx.y, t = threadIdx.x;
  __shared__ float h1[D_];
  const float xv = xq[b];
  #pragma unroll
  for (int i = 0; i < 8; ++i){
    int j = i*64 + t;
    h1[j] = gelu_f(xv * w1q[j] + b1q[j]);
  }
  __syncthreads();
  const int d = sl*64 + t;
  const float4* rw = (const float4*)(w2q + (size_t)d*D_);
  float a = 0.f;
  for (int kk = 0; kk < 128; ++kk){
    float4 hv = *(const float4*)&h1[kk*4];
    float4 wv = rw[kk];
    a += wv.x*hv.x + wv.y*hv.y + wv.z*hv.z + wv.w*hv.w;
  }
  h2g[b*D_ + d] = a + b2q[d];
}

// stage 2: qv = qw @ h2 + qb
__global__ __launch_bounds__(64)
void k_q3(const float* __restrict__ h2g,
          const float* __restrict__ qw, const float* __restrict__ qb,
          float* __restrict__ qvg){
  const int b = blockIdx.x, sl = blockIdx.y, t = threadIdx.x;
  __shared__ float h2[D_];
  #pragma unroll
  for (int i = 0; i < 8; ++i) h2[i*64 + t] = h2g[b*D_ + i*64 + t];
  __syncthreads();
  const int d = sl*64 + t;
  const float4* rw = (const float4*)(qw + (size_t)d*D_);
  float a = 0.f;
  for (int kk = 0; kk < 128; ++kk){
    float4 hv = *(const float4*)&h2[kk*4];
    float4 wv = rw[kk];
    a += wv.x*hv.x + wv.y*hv.y + wv.z*hv.z + wv.w*hv.w;
  }
  qvg[b*D_ + d] = a + qb[d];
}

// stage 3: qk[b][d] = c * sum_j qv[j] * kw[j][d]
__global__ __launch_bounds__(64)
void k_q4(const float* __restrict__ qvg, const float* __restrict__ kw,
          float* __restrict__ qk_out){
  const int b = blockIdx.x, sl = blockIdx.y, t = threadIdx.x;
  __shared__ float qv[D_];
  #pragma unroll
  for (int i = 0; i < 8; ++i) qv[i*64 + t] = qvg[b*D_ + i*64 + t];
  __syncthreads();
  const int d = sl*64 + t;
  float c0 = 0.f;
  for (int j = 0; j < D_; ++j) c0 += qv[j] * kw[(size_t)j*D_ + d];
  qk_out[b*D_ + d] = 0.04419417382415922f * c0;  // 512^-0.5
}

// ---------------- main: 128 items/block, 512 thr (8 waves x 64 cols), packed weights ----------------
__global__ __launch_bounds__(512, 2)
void k_main(const float* __restrict__ x,                 // [B,N,DI]
            const unsigned short* __restrict__ w1p,      // packed bf16
            const float* __restrict__ b1,
            const unsigned short* __restrict__ w2p,      // packed bf16
            const float* __restrict__ b2,
            const float* __restrict__ qk,                // [B,D]
            float* __restrict__ part,                    // [B,NT,D]
            float* __restrict__ esum){                   // [B,NT]
  const int tile = blockIdx.x;       // 0..63
  const int b = blockIdx.y;          // 0..31
  const int n0 = tile * TN_;
  const int t = threadIdx.x;         // 0..511
  const int lane = t & 63;
  const int wid = t >> 6;            // 0..7
  const int ln = lane & 15;
  const int q  = lane >> 4;          // 0..3

  __shared__ unsigned short h1s[TN_ * LROW_];   // 133120 B; low part aliased as x_lds
  __shared__ float s_ws[8][TN_];
  __shared__ float e_lds[TN_];

  // ---- stage x tile to LDS as bf16 (x_lds aliases h1s[0..TN_*XROW_)) ----
  {
    const float4* xb4 = (const float4*)(x + ((size_t)b * N_ + n0) * DI_);
    #pragma unroll
    for (int i = 0; i < 8; ++i){
      const int f = i*512 + t;            // float4 index; 32 float4 per row
      float4 v = xb4[f];
      const int m = f >> 5;
      const int k = (f & 31) << 2;
      uint2 pk;
      pk.x = pk2bf(v.x, v.y);
      pk.y = pk2bf(v.z, v.w);
      *(uint2*)&h1s[m*XROW_ + k] = pk;
    }
  }
  __syncthreads();

  const int jb = wid * 64;              // this wave's 64-col j block
  const unsigned short* w1base = w1p + (jb + ln)*32 + q*8;
  const unsigned short* w2base = w2p + (jb + ln)*32 + q*8;

  f4v acc[32];
  #pragma unroll
  for (int i = 0; i < 32; ++i) acc[i] = (f4v){0.f,0.f,0.f,0.f};

  // ---- GEMM1: h1^T[j,m] = sum_k w1[j,k] * x[m,k] ----
  #pragma unroll
  for (int kk = 0; kk < 4; ++kk){
    const int k = kk*32 + q*8;
    s8v aw[4];
    #pragma unroll
    for (int jt = 0; jt < 4; ++jt)
      aw[jt] = *(const s8v*)(w1base + kk*(D_*32) + jt*(16*32));
    s8v bx[8];
    #pragma unroll
    for (int mi = 0; mi < 8; ++mi)
      bx[mi] = *(const s8v*)&h1s[(mi*16 + ln)*XROW_ + k];
    #pragma unroll
    for (int jt = 0; jt < 4; ++jt)
      #pragma unroll
      for (int mi = 0; mi < 8; ++mi)
        acc[jt*8+mi] = __builtin_amdgcn_mfma_f32_16x16x32_bf16(aw[jt], bx[mi], acc[jt*8+mi], 0,0,0);
  }
  __syncthreads();   // all waves done reading x_lds before h1s overwrite

  // ---- bias + exact GELU + pack to row-major h1s[m][k] ----
  #pragma unroll
  for (int jt = 0; jt < 4; ++jt){
    const int j0 = jb + jt*16 + q*4;
    const float bv0 = b1[j0], bv1 = b1[j0+1], bv2 = b1[j0+2], bv3 = b1[j0+3];
    #pragma unroll
    for (int mi = 0; mi < 8; ++mi){
      const int m = mi*16 + ln;
      f4v v = acc[jt*8+mi];
      uint2 pk;
      pk.x = pk2bf(gelu_f(v[0]+bv0), gelu_f(v[1]+bv1));
      pk.y = pk2bf(gelu_f(v[2]+bv2), gelu_f(v[3]+bv3));
      *(uint2*)&h1s[m*LROW_ + j0] = pk;
    }
  }
  __syncthreads();

  #pragma unroll
  for (int i = 0; i < 32; ++i) acc[i] = (f4v){0.f,0.f,0.f,0.f};

  // ---- GEMM2: h2[m,j2] = sum_k h1[m,k] * w2[j2,k]; wave owns 64 j2 cols ----
  #pragma unroll 2
  for (int kk = 0; kk < 16; ++kk){
    const int k = kk*32 + q*8;
    s8v ah[8];
    #pragma unroll
    for (int mi = 0; mi < 8; ++mi)
      ah[mi] = *(const s8v*)&h1s[(mi*16 + ln)*LROW_ + k];
    s8v bw[4];
    #pragma unroll
    for (int ni = 0; ni < 4; ++ni)
      bw[ni] = *(const s8v*)(w2base + kk*(D_*32) + ni*(16*32));
    #pragma unroll
    for (int mi = 0; mi < 8; ++mi)
      #pragma unroll
      for (int ni = 0; ni < 4; ++ni)
        acc[mi*4+ni] = __builtin_amdgcn_mfma_f32_16x16x32_bf16(ah[mi], bw[ni], acc[mi*4+ni], 0,0,0);
  }

  // ---- bias + qk dot ----
  float b2v[4], qkv[4];
  #pragma unroll
  for (int ni = 0; ni < 4; ++ni){
    const int j2 = jb + ni*16 + ln;
    b2v[ni] = b2[j2];
    qkv[ni] = qk[b*D_ + j2];
  }
  #pragma unroll
  for (int mi = 0; mi < 8; ++mi)
    #pragma unroll
    for (int ni = 0; ni < 4; ++ni)
      #pragma unroll
      for (int r = 0; r < 4; ++r)
        acc[mi*4+ni][r] += b2v[ni];

  // partial scores over this wave's 64 cols (m = mi*16 + q*4 + r, col = ln)
  #pragma unroll
  for (int mi = 0; mi < 8; ++mi){
    #pragma unroll
    for (int r = 0; r < 4; ++r){
      float sp = 0.f;
      #pragma unroll
      for (int ni = 0; ni < 4; ++ni) sp += qkv[ni] * acc[mi*4+ni][r];
      sp += __shfl_xor(sp, 1, 64);
      sp += __shfl_xor(sp, 2, 64);
      sp += __shfl_xor(sp, 4, 64);
      sp += __shfl_xor(sp, 8, 64);
      if (ln == ((mi*4 + r) & 15)) s_ws[wid][mi*16 + q*4 + r] = sp;
    }
  }
  __syncthreads();

  if (t < TN_){
    float s = 0.f;
    #pragma unroll
    for (int w = 0; w < 8; ++w) s += s_ws[w][t];
    e_lds[t] = __expf(s);   // |s| small; constant shift cancels in softmax
  }
  __syncthreads();
  if (t < 64){
    float tot = wsum64(e_lds[t] + e_lds[t+64]);
    if (t == 0) esum[b*NT_ + tile] = tot;
  }

  // weighted h2 partial: part[b][tile][col] = sum_m e_m * h2[m,col]
  {
    float ev[8][4];
    #pragma unroll
    for (int mi = 0; mi < 8; ++mi)
      #pragma unroll
      for (int r = 0; r < 4; ++r)
        ev[mi][r] = e_lds[mi*16 + q*4 + r];
    #pragma unroll
    for (int ni = 0; ni < 4; ++ni){
      float zp = 0.f;
      #pragma unroll
      for (int mi = 0; mi < 8; ++mi)
        #pragma unroll
        for (int r = 0; r < 4; ++r)
          zp += ev[mi][r] * acc[mi*4+ni][r];
      zp += __shfl_xor(zp, 16, 64);
      zp += __shfl_xor(zp, 32, 64);
      if (lane < 16)
        part[((size_t)(b*NT_ + tile))*D_ + jb + ni*16 + ln] = zp;
    }
  }
}

// ---------------- final path, wide ----------------
// u[b][col] = (1/sum e) * sum_tl part[b][tl][col];  grid (32,4) x 128
__global__ __launch_bounds__(128)
void k_fu(const float* __restrict__ part, const float* __restrict__ esum,
          float* __restrict__ u){
  const int b = blockIdx.x, sl = blockIdx.y, t = threadIdx.x;
  float p = esum[b*NT_ + (t & 63)];
  p = wsum64(p);
  const float linv = 1.0f / p;
  const int col = sl*128 + t;
  const float* pb = part + (size_t)b*NT_*D_ + col;
  float s = 0.f;
  for (int tl = 0; tl < NT_; ++tl) s += pb[tl*D_];
  u[b*D_ + col] = s * linv;
}

// z = vw @ u + vb;  grid (32,8) x 64
__global__ __launch_bounds__(64)
void k_fz(const float* __restrict__ u, const float* __restrict__ vw,
          const float* __restrict__ vb, float* __restrict__ z){
  const int b = blockIdx.x, sl = blockIdx.y, t = threadIdx.x;
  __shared__ float su[D_];
  #pragma unroll
  for (int i = 0; i < 8; ++i) su[i*64 + t] = u[b*D_ + i*64 + t];
  __syncthreads();
  const int d = sl*64 + t;
  const float4* rw = (const float4*)(vw + (size_t)d*D_);
  float a = 0.f;
  for (int kk = 0; kk < 128; ++kk){
    float4 uv = *(const float4*)&su[kk*4];
    float4 wv = rw[kk];
    a += wv.x*uv.x + wv.y*uv.y + wv.z*uv.z + wv.w*uv.w;
  }
  z[b*D_ + d] = a + vb[d];
}

// h = gelu(pw1 @ z + pb1);  grid (32,8) x 64
__global__ __launch_bounds__(64)
void k_fh(const float* __restrict__ z, const float* __restrict__ pw1,
          const float* __restrict__ pb1, float* __restrict__ h){
  const int b = blockIdx.x, sl = blockIdx.y, t = threadIdx.x;
  __shared__ float sz[D_];
  #pragma unroll
  for (int i = 0; i < 8; ++i) sz[i*64 + t] = z[b*D_ + i*64 + t];
  __syncthreads();
  const int d = sl*64 + t;
  const float4* rw = (const float4*)(pw1 + (size_t)d*D_);
  float a = 0.f;
  for (int kk = 0; kk < 128; ++kk){
    float4 zv = *(const float4*)&sz[kk*4];
    float4 wv = rw[kk];
    a += wv.x*zv.x + wv.y*zv.y + wv.z*zv.z + wv.w*zv.w;
  }
  h[b*D_ + d] = gelu_f(a + pb1[d]);
}

// out = pw2 @ h + pb2;  grid (32,16) x 64
__global__ __launch_bounds__(64)
void k_fo(const float* __restrict__ h, const float* __restrict__ pw2,
          const float* __restrict__ pb2, float* __restrict__ out){
  const int b = blockIdx.x, sl = blockIdx.y, t = threadIdx.x;
  __shared__ float sh[D_];
  #pragma unroll
  for (int i = 0; i < 8; ++i) sh[i*64 + t] = h[b*D_ + i*64 + t];
  __syncthreads();
  const int c = sl*64 + t;
  if (c < NC_){
    const float4* rw = (const float4*)(pw2 + (size_t)c*D_);
    float a = 0.f;
    for (int kk = 0; kk < 128; ++kk){
      float4 hv = *(const float4*)&sh[kk*4];
      float4 wv = rw[kk];
      a += wv.x*hv.x + wv.y*hv.y + wv.z*hv.z + wv.w*hv.w;
    }
    out[(size_t)b*NC_ + c] = a + pb2[c];
  }
}

extern "C" void kernel_launch(void* const* d_in, const int* in_sizes, int n_in,
                              void* d_out, int out_size, void* d_ws, size_t ws_size,
                              hipStream_t stream) {
  (void)in_sizes; (void)n_in; (void)out_size; (void)ws_size;
  const float* x_items  = (const float*)d_in[0];
  const float* x_query  = (const float*)d_in[1];
  const float* psi_x_w1 = (const float*)d_in[2];
  const float* psi_x_b1 = (const float*)d_in[3];
  const float* psi_x_w2 = (const float*)d_in[4];
  const float* psi_x_b2 = (const float*)d_in[5];
  const float* psi_q_w1 = (const float*)d_in[6];
  const float* psi_q_b1 = (const float*)d_in[7];
  const float* psi_q_w2 = (const float*)d_in[8];
  const float* psi_q_b2 = (const float*)d_in[9];
  const float* q_w      = (const float*)d_in[10];
  const float* q_b      = (const float*)d_in[11];
  const float* k_w      = (const float*)d_in[12];
  // k_b (d_in[13]) unused: constant score shift cancels in softmax
  const float* v_w      = (const float*)d_in[14];
  const float* v_b      = (const float*)d_in[15];
  const float* phi_w1   = (const float*)d_in[16];
  const float* phi_b1   = (const float*)d_in[17];
  const float* phi_w2   = (const float*)d_in[18];
  const float* phi_b2   = (const float*)d_in[19];
  float* out = (float*)d_out;

  char* ws = (char*)d_ws;
  unsigned short* w1p = (unsigned short*)(ws);                 // 131072
  unsigned short* w2p = (unsigned short*)(ws + 131072);        // 524288
  float* qk   = (float*)(ws + 655360);                         // 65536
  float* part = (float*)(ws + 720896);                         // 4194304
  float* esum = (float*)(ws + 4915200);                        // 8192
  float* h2g  = (float*)(ws + 4923392);                        // 65536
  float* qvg  = (float*)(ws + 4988928);                        // 65536
  float* ub   = (float*)(ws + 5054464);                        // 65536
  float* zb   = (float*)(ws + 5120000);                        // 65536
  float* hb   = (float*)(ws + 5185536);                        // 65536

  hipLaunchKernelGGL(k_prep, dim3(1024), dim3(256), 0, stream,
                     psi_x_w1, psi_x_w2, w1p, w2p);
  hipLaunchKernelGGL(k_q2, dim3(32, 8), dim3(64), 0, stream,
                     x_query, psi_q_w1, psi_q_b1, psi_q_w2, psi_q_b2, h2g);
  hipLaunchKernelGGL(k_q3, dim3(32, 8), dim3(64), 0, stream,
                     h2g, q_w, q_b, qvg);
  hipLaunchKernelGGL(k_q4, dim3(32, 8), dim3(64), 0, stream,
                     qvg, k_w, qk);
  hipLaunchKernelGGL(k_main, dim3(NT_, B_), dim3(512), 0, stream,
                     x_items, w1p, psi_x_b1, w2p, psi_x_b2, qk, part, esum);
  hipLaunchKernelGGL(k_fu, dim3(32, 4), dim3(128), 0, stream,
                     part, esum, ub);
  hipLaunchKernelGGL(k_fz, dim3(32, 8), dim3(64), 0, stream,
                     ub, v_w, v_b, zb);
  hipLaunchKernelGGL(k_fh, dim3(32, 8), dim3(64), 0, stream,
                     zb, phi_w1, phi_b1, hb);
  hipLaunchKernelGGL(k_fo, dim3(32, 16), dim3(64), 0, stream,
                     hb, phi_w2, phi_b2, out);
}